// Round 12
// baseline (158.886 us; speedup 1.0000x reference)
//
#include <hip/hip_runtime.h>
#include <math.h>

// Capsule conv + dynamic routing via fp16 MFMA (16x16x32), swapped operands:
// A = prepped fp16 weights (M = f), B = LDS input patch (N = px).
// R22 (resubmit after infra flake): PERSISTENT TWO-TILE BLOCK with
// cross-round overlap. R21 regression (+10us from doubling A-issues) proved
// conv is VMEM/L2-path bound, not LDS-pipe bound; register audit: 116
// regs/thread -> 1 block/CU resident -> every kernel since R12 ran 2
// sequential ~21us rounds. This kernel keeps the R18 per-wave economy
// EXACTLY (best known) but each block owns two consecutive tiles: after
// conv(t0) it issues async global_load_lds of t1's x-rows into an fp32 LDS
// buffer (zero VGPR); the DMA latency+drain hides under routing(t0)'s ~14k
// cycles; a cheap LDS->LDS convert then builds the fp16 patch for round 2 -
// no exposed staging, no second dispatch round. OOB rows: clamped global
// src, zeroed at convert. LDS 145.5KB (1 block/CU by design). Grid 256.
// NOTE: hipLaunchCooperativeKernel is NOT graph-capturable here (R7 failed);
// ~44us d_ws re-poison fill + ~12us restore/launch are fixed harness overhead.
//
// x:    [B=32][H=32][W=32][128] fp32 (128 = i*16+cin)
// wts:  [i=8][k=144][o=128] fp32 -> w16[(i*5+q)][c][lane][j]
//       = wts[(i*144 + q*32 + (lane>>4)*8 + j)*128 + c*16 + (lane&15)], 0 for k>=144
// out:  [B][H][W][128] fp32 (o = c*16+f)
//
// Block = 1024 = 16 waves; wave w: c = w&7, g = w>>3; per tile: 2 rows x 32 px.
// Grid = 256; block handles tiles t0 = 2*bid, t1 = 2*bid+1 (same batch b,
// rows h0,h0+1 then h0+2,h0+3). Slot s = g*32 + mt*16 + l15 (0..63).
// MFMA 16x16x32: A[m=lane&15 -> f][k=quad*8+j], B[k][n=lane&15 -> px(mt)].

typedef _Float16 fp16x8 __attribute__((ext_vector_type(8)));
typedef float f32x4 __attribute__((ext_vector_type(4)));

#define EPS 1e-7f
constexpr int PSTRIDE = 136;   // fp16 elems; 272B row stride: 16B-aligned, 2-way banks (free)
constexpr int PCOLS   = 34;    // 32 px + 2 halo
constexpr int PROWS   = 4;     // rows h-1..h+2
constexpr int NSTG    = PROWS * PCOLS * 32;   // 4352 float4 staging chunks
constexpr int LSTRIDE = 76;    // lg_arr: [slot*76 + i*9 + c]
constexpr int PXS     = 76;    // r_arr:  [slot*76 + c*8 + i]; b128 stride 304B -> 2-way (free)
constexpr int W_ELEMS = 40 * 8 * 64 * 8;   // 163840

// sum across the 4 quads (lanes ^16, ^32); all lanes receive the total
__device__ __forceinline__ float sumquad(float v) {
    v += __shfl_xor(v, 16);
    v += __shfl_xor(v, 32);
    return v;
}

// async global->LDS, 16B per lane; LDS dest must be wave-uniform base (+lane*16)
__device__ __forceinline__ void gll16(const float4* g, float4* l) {
    __builtin_amdgcn_global_load_lds(
        (const __attribute__((address_space(1))) unsigned int*)(const void*)g,
        (__attribute__((address_space(3))) unsigned int*)(void*)l, 16, 0, 0);
}

// prep: direct scatter, 640 blocks x 256 threads, 1 element each (R8-proven).
__global__ __launch_bounds__(256)
void prep_weights(const float* __restrict__ wts,
                  _Float16* __restrict__ w16) {
    int n = blockIdx.x * 256 + threadIdx.x;        // 0..163839
    if (n >= W_ELEMS) return;
    int j    = n & 7;
    int ln   = (n >> 3) & 63;
    int c0   = (n >> 9) & 7;
    int iq   = n >> 12;                            // i*5+q
    int i0   = iq / 5;
    int q0   = iq - i0 * 5;
    int k = q0 * 32 + (ln >> 4) * 8 + j;
    float w = 0.f;
    if (k < 144) w = wts[(i0 * 144 + k) * 128 + c0 * 16 + (ln & 15)];
    w16[n] = (_Float16)w;                          // RNE
}

__global__ __launch_bounds__(1024, 4)
void capsule_mfma_kernel(const float* __restrict__ x,
                         const _Float16* __restrict__ w16,
                         const float* __restrict__ bias,
                         float* __restrict__ out)
{
    __shared__ _Float16 patch[PROWS * PCOLS * PSTRIDE];  // 36992 B
    __shared__ float4 stage32[NSTG];                     // 69632 B (t1 raw fp32)
    __shared__ float lg_arr[64 * LSTRIDE];               // 19456 B
    __shared__ float r_arr[64 * PXS];                    // 19456 B
                                                         // total 145536 B

    const int tid  = threadIdx.x;
    const int lane = tid & 63;
    const int w    = tid >> 6;     // 0..15
    const int c    = w & 7;        // output capsule
    const int g    = w >> 3;       // output row offset (0/1)
    const int l15  = lane & 15;    // A: f ; B & D: px-in-tile
    const int quad = lane >> 4;
    const int lane8 = lane * 8;

    const int bid = blockIdx.x;            // 0..255
    const int t0  = bid * 2;               // tiles t0, t0+1
    const int h2  = t0 & 15;               // even
    const int b   = t0 >> 4;
    const int h0  = h2 << 1;               // tile0 rows h0,h0+1; tile1 rows h0+2,h0+3

    const float4* x4 = (const float4*)x;

    // ---- B (patch) per-lane offsets: k = q*32 + quad*8 + j; tap = 2q+(quad>>1) ----
    int a_off[5];
    #pragma unroll
    for (int q = 0; q < 5; ++q) {
        int tap = 2 * q + (quad >> 1);
        if (tap > 8) tap = 8;                 // pad region: A is zero there
        int dy = tap / 3, dx = tap - dy * 3;
        a_off[q] = ((g + dy) * PCOLS + l15 + dx) * PSTRIDE + (quad & 1) * 8;
    }

    const float4 bb4 = *(const float4*)(bias + c * 16 + quad * 4);
    const float barr[4] = {bb4.x, bb4.y, bb4.z, bb4.w};

    for (int s = 0; s < 2; ++s) {
        const int h = h0 + 2 * s;

        // ---- build fp16 patch for this tile ----
        if (s == 0) {
            // direct stage: global fp32 -> cvt -> patch fp16
            for (int idx = tid; idx < NSTG; idx += 1024) {
                int ch4  = idx & 31;
                int slot = idx >> 5;               // row*34 + colp
                int row  = slot / PCOLS;
                int colp = slot - row * PCOLS;
                int gh = h - 1 + row;
                int gw = colp - 1;
                float4 v = {0.f, 0.f, 0.f, 0.f};
                if ((unsigned)gh < 32u && (unsigned)gw < 32u)
                    v = x4[(((b * 32 + gh) * 32 + gw) << 5) + ch4];
                _Float16 ph[4];
                ph[0] = (_Float16)v.x; ph[1] = (_Float16)v.y;
                ph[2] = (_Float16)v.z; ph[3] = (_Float16)v.w;
                *(ushort4*)&patch[slot * PSTRIDE + ch4 * 4] = *(const ushort4*)ph;
            }
        } else {
            // convert pre-DMA'd fp32 rows (stage32) -> patch fp16; zero OOB
            for (int idx = tid; idx < NSTG; idx += 1024) {
                int ch4  = idx & 31;
                int slot = idx >> 5;
                int row  = slot / PCOLS;
                int colp = slot - row * PCOLS;
                int gh = h - 1 + row;
                int gw = colp - 1;
                float4 v = {0.f, 0.f, 0.f, 0.f};
                if ((unsigned)gh < 32u && (unsigned)gw < 32u)
                    v = stage32[idx];
                _Float16 ph[4];
                ph[0] = (_Float16)v.x; ph[1] = (_Float16)v.y;
                ph[2] = (_Float16)v.z; ph[3] = (_Float16)v.w;
                *(ushort4*)&patch[slot * PSTRIDE + ch4 * 4] = *(const ushort4*)ph;
            }
        }
        __syncthreads();

        // ---- conv via MFMA: 40 steps of (1 A b128, 2 B ds_read b128, 2 MFMA) ----
        f32x4 acc[2][8];
        #pragma unroll
        for (int mt = 0; mt < 2; ++mt)
            #pragma unroll
            for (int i = 0; i < 8; ++i) acc[mt][i] = (f32x4){0.f, 0.f, 0.f, 0.f};

        #pragma unroll
        for (int q = 0; q < 5; ++q) {
            #pragma unroll
            for (int i = 0; i < 8; ++i) {
                int woff = ((i * 5 + q) * 8 + c) * 512 + lane8;
                fp16x8 aw = *(const fp16x8*)(w16 + woff);
                fp16x8 b0 = *(const fp16x8*)(patch + a_off[q] + i * 16);
                fp16x8 b1 = *(const fp16x8*)(patch + a_off[q] + 16 * PSTRIDE + i * 16);
                acc[0][i] = __builtin_amdgcn_mfma_f32_16x16x32_f16(aw, b0, acc[0][i], 0, 0, 0);
                acc[1][i] = __builtin_amdgcn_mfma_f32_16x16x32_f16(aw, b1, acc[1][i], 0, 0, 0);
            }
        }

        if (s == 0) {
            // ---- issue async DMA of tile1's x rows into stage32 (fp32) ----
            // latency + barrier drain hide under routing(t0) below.
            const int h1 = h0 + 2;
            for (int idx = tid; idx < NSTG; idx += 1024) {
                int ch4  = idx & 31;
                int slot = idx >> 5;
                int row  = slot / PCOLS;
                int colp = slot - row * PCOLS;
                int gh = h1 - 1 + row;
                int gw = colp - 1;
                int sgh = ((unsigned)gh < 32u) ? gh : 0;   // clamp: OOB zeroed at convert
                int sgw = ((unsigned)gw < 32u) ? gw : 0;
                const float4* src = x4 + ((((b * 32 + sgh) * 32 + sgw) << 5) + ch4);
                gll16(src, stage32 + (idx - lane));        // wave-uniform LDS base
            }
        }

        // ---- dynamic routing: thread owns (slot = g*32+mt*16+l15, c, f) ----
        float actv[2][4];

        // iter 0: route = 1/8 uniform
        #pragma unroll
        for (int mt = 0; mt < 2; ++mt) {
            float pre[4];
            #pragma unroll
            for (int r = 0; r < 4; ++r) {
                float ss = acc[mt][0][r] + acc[mt][1][r] + acc[mt][2][r] + acc[mt][3][r]
                         + acc[mt][4][r] + acc[mt][5][r] + acc[mt][6][r] + acc[mt][7][r];
                pre[r] = ss * 0.125f + barr[r];
            }
            float s2 = sumquad(pre[0]*pre[0] + pre[1]*pre[1] + pre[2]*pre[2] + pre[3]*pre[3]);
            float scale = s2 * __builtin_amdgcn_rsqf(s2 + EPS) * __builtin_amdgcn_rcpf(1.f + s2);
            #pragma unroll
            for (int r = 0; r < 4; ++r) actv[mt][r] = scale * pre[r];
        }
        #pragma unroll
        for (int mt = 0; mt < 2; ++mt) {
            int slot = g * 32 + mt * 16 + l15;
            #pragma unroll
            for (int i = 0; i < 8; ++i) {
                float t = acc[mt][i][0]*actv[mt][0] + acc[mt][i][1]*actv[mt][1]
                        + acc[mt][i][2]*actv[mt][2] + acc[mt][i][3]*actv[mt][3];
                t = sumquad(t);
                if (quad == 0) lg_arr[slot * LSTRIDE + i * 9 + c] = t;
            }
        }
        __syncthreads();
        if (tid < 512) {   // softmax over c for each (slot, i): 64*8 = 512 tasks
            int p = tid >> 3, ii = tid & 7;
            const float* lrow = &lg_arr[p * LSTRIDE + ii * 9];
            float m = lrow[0];
            #pragma unroll
            for (int cc = 1; cc < 8; ++cc) m = fmaxf(m, lrow[cc]);
            float e[8]; float den = 0.f;
            #pragma unroll
            for (int cc = 0; cc < 8; ++cc) { e[cc] = __expf(lrow[cc] - m); den += e[cc]; }
            float rd = __builtin_amdgcn_rcpf(den);
            #pragma unroll
            for (int cc = 0; cc < 8; ++cc) r_arr[p * PXS + cc * 8 + ii] = e[cc] * rd;
        }
        __syncthreads();

        // iter 1
        #pragma unroll
        for (int mt = 0; mt < 2; ++mt) {
            int slot = g * 32 + mt * 16 + l15;
            const float4* rp = (const float4*)&r_arr[slot * PXS + c * 8];
            float4 r0 = rp[0], r1 = rp[1];
            float pre[4];
            #pragma unroll
            for (int r = 0; r < 4; ++r) {
                float ss;
                ss = r0.x * acc[mt][0][r]; ss = fmaf(r0.y, acc[mt][1][r], ss);
                ss = fmaf(r0.z, acc[mt][2][r], ss); ss = fmaf(r0.w, acc[mt][3][r], ss);
                ss = fmaf(r1.x, acc[mt][4][r], ss); ss = fmaf(r1.y, acc[mt][5][r], ss);
                ss = fmaf(r1.z, acc[mt][6][r], ss); ss = fmaf(r1.w, acc[mt][7][r], ss);
                pre[r] = ss + barr[r];
            }
            float s2 = sumquad(pre[0]*pre[0] + pre[1]*pre[1] + pre[2]*pre[2] + pre[3]*pre[3]);
            float scale = s2 * __builtin_amdgcn_rsqf(s2 + EPS) * __builtin_amdgcn_rcpf(1.f + s2);
            #pragma unroll
            for (int r = 0; r < 4; ++r) actv[mt][r] = scale * pre[r];
        }
        #pragma unroll
        for (int mt = 0; mt < 2; ++mt) {
            int slot = g * 32 + mt * 16 + l15;
            #pragma unroll
            for (int i = 0; i < 8; ++i) {
                float t = acc[mt][i][0]*actv[mt][0] + acc[mt][i][1]*actv[mt][1]
                        + acc[mt][i][2]*actv[mt][2] + acc[mt][i][3]*actv[mt][3];
                t = sumquad(t);
                if (quad == 0) lg_arr[slot * LSTRIDE + i * 9 + c] += t;
            }
        }
        __syncthreads();
        if (tid < 512) {
            int p = tid >> 3, ii = tid & 7;
            const float* lrow = &lg_arr[p * LSTRIDE + ii * 9];
            float m = lrow[0];
            #pragma unroll
            for (int cc = 1; cc < 8; ++cc) m = fmaxf(m, lrow[cc]);
            float e[8]; float den = 0.f;
            #pragma unroll
            for (int cc = 0; cc < 8; ++cc) { e[cc] = __expf(lrow[cc] - m); den += e[cc]; }
            float rd = __builtin_amdgcn_rcpf(den);
            #pragma unroll
            for (int cc = 0; cc < 8; ++cc) r_arr[p * PXS + cc * 8 + ii] = e[cc] * rd;
        }
        __syncthreads();

        // iter 2: final activation -> out (per-lane float4: f = quad*4 + 0..3)
        #pragma unroll
        for (int mt = 0; mt < 2; ++mt) {
            int slot = g * 32 + mt * 16 + l15;
            const float4* rp = (const float4*)&r_arr[slot * PXS + c * 8];
            float4 r0 = rp[0], r1 = rp[1];
            float pre[4];
            #pragma unroll
            for (int r = 0; r < 4; ++r) {
                float ss;
                ss = r0.x * acc[mt][0][r]; ss = fmaf(r0.y, acc[mt][1][r], ss);
                ss = fmaf(r0.z, acc[mt][2][r], ss); ss = fmaf(r0.w, acc[mt][3][r], ss);
                ss = fmaf(r1.x, acc[mt][4][r], ss); ss = fmaf(r1.y, acc[mt][5][r], ss);
                ss = fmaf(r1.z, acc[mt][6][r], ss); ss = fmaf(r1.w, acc[mt][7][r], ss);
                pre[r] = ss + barr[r];
            }
            float s2 = sumquad(pre[0]*pre[0] + pre[1]*pre[1] + pre[2]*pre[2] + pre[3]*pre[3]);
            float scale = s2 * __builtin_amdgcn_rsqf(s2 + EPS) * __builtin_amdgcn_rcpf(1.f + s2);
            float4 o4 = { scale*pre[0], scale*pre[1], scale*pre[2], scale*pre[3] };
            int gh = h + g;
            int px = mt * 16 + l15;
            *(float4*)(out + (((b * 32 + gh) * 32 + px) << 7) + c * 16 + quad * 4) = o4;
        }
        // loop to tile1: convert-phase barrier at top of s=1 orders
        // patch overwrite vs this tile's conv reads (routing barriers already
        // separate them) and stage32 reads vs the DMA (vmcnt drained at the
        // first routing barrier above).
    }
}

extern "C" void kernel_launch(void* const* d_in, const int* in_sizes, int n_in,
                              void* d_out, int out_size, void* d_ws, size_t ws_size,
                              hipStream_t stream) {
    const float* x    = (const float*)d_in[0];
    const float* wts  = (const float*)d_in[1];
    const float* bias = (const float*)d_in[2];
    float* out        = (float*)d_out;
    _Float16* w16     = (_Float16*)d_ws;

    prep_weights<<<dim3(640), dim3(256), 0, stream>>>(wts, w16);
    capsule_mfma_kernel<<<dim3(256), dim3(1024), 0, stream>>>(x, w16, bias, out);
}

// Round 13
// 101.679 us; speedup vs baseline: 1.5626x; 1.5626x over previous
//
#include <hip/hip_runtime.h>
#include <math.h>

// Capsule conv + dynamic routing via fp16 MFMA (16x16x32), swapped operands:
// A = prepped fp16 weights (M = f), B = LDS input patch (N = px).
// R23: REVERT to R18 (best harness-verified: 102.34us). R22's two-tile
// persistence spilled (VGPR 64 + 64 AGPR = exactly the 128-reg budget;
// 167MB scratch fetch+write). Structural closure: the per-i votes a CU holds
// through routing = 256KB = half the 512KB CU register file -> exactly one
// votes-set (16 waves) resident; a second is impossible (needs <=64 regs/thr)
// and LDS can't hold it. Hence the 2-round x ~21us floor: R12/R13/R15/R18/R21
// (five geometries, incl. free cross-block overlap at 2-resident in R12) all
// land at 42+/-5us main-kernel; A-traffic x0.5/x2, A-latency restructure,
// B-read halving, occupancy 6->32 waves, cross-round DMA all neutral/worse.
// NOTE: hipLaunchCooperativeKernel is NOT graph-capturable here (R7 failed);
// ~44us d_ws re-poison fill + ~12us restore/launch are fixed harness overhead.
//
// x:    [B=32][H=32][W=32][128] fp32 (128 = i*16+cin)
// wts:  [i=8][k=144][o=128] fp32 -> w16[(i*5+q)][c][lane][j]
//       = wts[(i*144 + q*32 + (lane>>4)*8 + j)*128 + c*16 + (lane&15)], 0 for k>=144
// out:  [B][H][W][128] fp32 (o = c*16+f)
//
// Block = 1024 = 16 waves; wave w: c = w&7, g = w>>3; 2 rows x 32 px.
// Grid = 512 (b*16 + h2), h = 2*h2. Slot s = g*32 + mt*16 + l15 (0..63):
// output row = h+g, px-in-row = mt*16+l15.
// MFMA 16x16x32: A[m=lane&15 -> f][k=quad*8+j], B[k][n=lane&15 -> px(mt)].
// D: f = quad*4 + reg.

typedef _Float16 fp16x8 __attribute__((ext_vector_type(8)));
typedef float f32x4 __attribute__((ext_vector_type(4)));

#define EPS 1e-7f
constexpr int PSTRIDE = 136;   // fp16 elems; 272B row stride: 16B-aligned, 2-way banks (free)
constexpr int PCOLS   = 34;    // 32 px + 2 halo
constexpr int PROWS   = 4;     // rows h-1..h+2
constexpr int LSTRIDE = 76;    // lg_arr: [slot*76 + i*9 + c]
constexpr int PXS     = 76;    // r_arr:  [slot*76 + c*8 + i]; b128 stride 304B -> 2-way (free)
constexpr int W_ELEMS = 40 * 8 * 64 * 8;   // 163840

// sum across the 4 quads (lanes ^16, ^32); all lanes receive the total
__device__ __forceinline__ float sumquad(float v) {
    v += __shfl_xor(v, 16);
    v += __shfl_xor(v, 32);
    return v;
}

// prep: direct scatter, 640 blocks x 256 threads, 1 element each (R8-proven).
__global__ __launch_bounds__(256)
void prep_weights(const float* __restrict__ wts,
                  _Float16* __restrict__ w16) {
    int n = blockIdx.x * 256 + threadIdx.x;        // 0..163839
    if (n >= W_ELEMS) return;
    int j    = n & 7;
    int ln   = (n >> 3) & 63;
    int c0   = (n >> 9) & 7;
    int iq   = n >> 12;                            // i*5+q
    int i0   = iq / 5;
    int q0   = iq - i0 * 5;
    int k = q0 * 32 + (ln >> 4) * 8 + j;
    float w = 0.f;
    if (k < 144) w = wts[(i0 * 144 + k) * 128 + c0 * 16 + (ln & 15)];
    w16[n] = (_Float16)w;                          // RNE
}

__global__ __launch_bounds__(1024, 4)
void capsule_mfma_kernel(const float* __restrict__ x,
                         const _Float16* __restrict__ w16,
                         const float* __restrict__ bias,
                         float* __restrict__ out)
{
    __shared__ _Float16 patch[PROWS * PCOLS * PSTRIDE];  // 36992 B
    __shared__ float lg_arr[64 * LSTRIDE];               // 19456 B
    __shared__ float r_arr[64 * PXS];                    // 19456 B

    const int tid  = threadIdx.x;
    const int lane = tid & 63;
    const int w    = tid >> 6;     // 0..15
    const int c    = w & 7;        // output capsule
    const int g    = w >> 3;       // output row offset (0/1)
    const int l15  = lane & 15;    // A: f ; B & D: px-in-tile
    const int quad = lane >> 4;
    const int lane8 = lane * 8;

    const int bid = blockIdx.x;
    const int h2 = bid & 15, b = bid >> 4;
    const int h = h2 << 1;         // output rows h, h+1

    // ---- stage input patch rows h-1..h+2, cols -1..32, fp16 ----
    const float4* x4 = (const float4*)x;
    for (int idx = tid; idx < PROWS * PCOLS * 32; idx += 1024) {
        int ch4  = idx & 31;
        int slot = idx >> 5;               // row*34 + colp
        int row  = slot / PCOLS;
        int colp = slot - row * PCOLS;
        int gh = h - 1 + row;
        int gw = colp - 1;
        float4 v = {0.f, 0.f, 0.f, 0.f};
        if ((unsigned)gh < 32u && (unsigned)gw < 32u)
            v = x4[(((b * 32 + gh) * 32 + gw) << 5) + ch4];
        _Float16 ph[4];
        ph[0] = (_Float16)v.x; ph[1] = (_Float16)v.y;
        ph[2] = (_Float16)v.z; ph[3] = (_Float16)v.w;
        *(ushort4*)&patch[slot * PSTRIDE + ch4 * 4] = *(const ushort4*)ph;
    }
    __syncthreads();

    // ---- B (patch) per-lane offsets: k = q*32 + quad*8 + j; tap = 2q+(quad>>1) ----
    // output row h+g -> tap rows (g+dy)
    int a_off[5];
    #pragma unroll
    for (int q = 0; q < 5; ++q) {
        int tap = 2 * q + (quad >> 1);
        if (tap > 8) tap = 8;                 // pad region: A is zero there
        int dy = tap / 3, dx = tap - dy * 3;
        a_off[q] = ((g + dy) * PCOLS + l15 + dx) * PSTRIDE + (quad & 1) * 8;
    }

    // ---- conv via MFMA: 40 steps of (1 A b128 from L1/L2, 2 B ds_read, 2 MFMA) ----
    f32x4 acc[2][8];
    #pragma unroll
    for (int mt = 0; mt < 2; ++mt)
        #pragma unroll
        for (int i = 0; i < 8; ++i) acc[mt][i] = (f32x4){0.f, 0.f, 0.f, 0.f};

    #pragma unroll
    for (int q = 0; q < 5; ++q) {
        #pragma unroll
        for (int i = 0; i < 8; ++i) {
            int woff = ((i * 5 + q) * 8 + c) * 512 + lane8;
            fp16x8 aw = *(const fp16x8*)(w16 + woff);
            fp16x8 b0 = *(const fp16x8*)(patch + a_off[q] + i * 16);
            fp16x8 b1 = *(const fp16x8*)(patch + a_off[q] + 16 * PSTRIDE + i * 16);
            acc[0][i] = __builtin_amdgcn_mfma_f32_16x16x32_f16(aw, b0, acc[0][i], 0, 0, 0);
            acc[1][i] = __builtin_amdgcn_mfma_f32_16x16x32_f16(aw, b1, acc[1][i], 0, 0, 0);
        }
    }

    // ---- dynamic routing: thread owns (slot = g*32+mt*16+l15, c, f = quad*4+0..3) ----
    const float4 bb4 = *(const float4*)(bias + c * 16 + quad * 4);
    const float barr[4] = {bb4.x, bb4.y, bb4.z, bb4.w};

    float actv[2][4];

    // iter 0: route = 1/8 uniform
    #pragma unroll
    for (int mt = 0; mt < 2; ++mt) {
        float pre[4];
        #pragma unroll
        for (int r = 0; r < 4; ++r) {
            float s = acc[mt][0][r] + acc[mt][1][r] + acc[mt][2][r] + acc[mt][3][r]
                    + acc[mt][4][r] + acc[mt][5][r] + acc[mt][6][r] + acc[mt][7][r];
            pre[r] = s * 0.125f + barr[r];
        }
        float s2 = sumquad(pre[0]*pre[0] + pre[1]*pre[1] + pre[2]*pre[2] + pre[3]*pre[3]);
        float scale = s2 * __builtin_amdgcn_rsqf(s2 + EPS) * __builtin_amdgcn_rcpf(1.f + s2);
        #pragma unroll
        for (int r = 0; r < 4; ++r) actv[mt][r] = scale * pre[r];
    }
    #pragma unroll
    for (int mt = 0; mt < 2; ++mt) {
        int slot = g * 32 + mt * 16 + l15;
        #pragma unroll
        for (int i = 0; i < 8; ++i) {
            float t = acc[mt][i][0]*actv[mt][0] + acc[mt][i][1]*actv[mt][1]
                    + acc[mt][i][2]*actv[mt][2] + acc[mt][i][3]*actv[mt][3];
            t = sumquad(t);
            if (quad == 0) lg_arr[slot * LSTRIDE + i * 9 + c] = t;
        }
    }
    __syncthreads();
    if (tid < 512) {   // softmax over c for each (slot, i): 64*8 = 512 tasks
        int p = tid >> 3, ii = tid & 7;
        const float* lrow = &lg_arr[p * LSTRIDE + ii * 9];
        float m = lrow[0];
        #pragma unroll
        for (int cc = 1; cc < 8; ++cc) m = fmaxf(m, lrow[cc]);
        float e[8]; float den = 0.f;
        #pragma unroll
        for (int cc = 0; cc < 8; ++cc) { e[cc] = __expf(lrow[cc] - m); den += e[cc]; }
        float rd = __builtin_amdgcn_rcpf(den);
        #pragma unroll
        for (int cc = 0; cc < 8; ++cc) r_arr[p * PXS + cc * 8 + ii] = e[cc] * rd;
    }
    __syncthreads();

    // iter 1
    #pragma unroll
    for (int mt = 0; mt < 2; ++mt) {
        int slot = g * 32 + mt * 16 + l15;
        const float4* rp = (const float4*)&r_arr[slot * PXS + c * 8];
        float4 r0 = rp[0], r1 = rp[1];
        float pre[4];
        #pragma unroll
        for (int r = 0; r < 4; ++r) {
            float s;
            s  = r0.x * acc[mt][0][r]; s = fmaf(r0.y, acc[mt][1][r], s);
            s  = fmaf(r0.z, acc[mt][2][r], s); s = fmaf(r0.w, acc[mt][3][r], s);
            s  = fmaf(r1.x, acc[mt][4][r], s); s = fmaf(r1.y, acc[mt][5][r], s);
            s  = fmaf(r1.z, acc[mt][6][r], s); s = fmaf(r1.w, acc[mt][7][r], s);
            pre[r] = s + barr[r];
        }
        float s2 = sumquad(pre[0]*pre[0] + pre[1]*pre[1] + pre[2]*pre[2] + pre[3]*pre[3]);
        float scale = s2 * __builtin_amdgcn_rsqf(s2 + EPS) * __builtin_amdgcn_rcpf(1.f + s2);
        #pragma unroll
        for (int r = 0; r < 4; ++r) actv[mt][r] = scale * pre[r];
    }
    #pragma unroll
    for (int mt = 0; mt < 2; ++mt) {
        int slot = g * 32 + mt * 16 + l15;
        #pragma unroll
        for (int i = 0; i < 8; ++i) {
            float t = acc[mt][i][0]*actv[mt][0] + acc[mt][i][1]*actv[mt][1]
                    + acc[mt][i][2]*actv[mt][2] + acc[mt][i][3]*actv[mt][3];
            t = sumquad(t);
            if (quad == 0) lg_arr[slot * LSTRIDE + i * 9 + c] += t;
        }
    }
    __syncthreads();
    if (tid < 512) {
        int p = tid >> 3, ii = tid & 7;
        const float* lrow = &lg_arr[p * LSTRIDE + ii * 9];
        float m = lrow[0];
        #pragma unroll
        for (int cc = 1; cc < 8; ++cc) m = fmaxf(m, lrow[cc]);
        float e[8]; float den = 0.f;
        #pragma unroll
        for (int cc = 0; cc < 8; ++cc) { e[cc] = __expf(lrow[cc] - m); den += e[cc]; }
        float rd = __builtin_amdgcn_rcpf(den);
        #pragma unroll
        for (int cc = 0; cc < 8; ++cc) r_arr[p * PXS + cc * 8 + ii] = e[cc] * rd;
    }
    __syncthreads();

    // iter 2: final activation -> out (per-lane float4: f = quad*4 + 0..3)
    #pragma unroll
    for (int mt = 0; mt < 2; ++mt) {
        int slot = g * 32 + mt * 16 + l15;
        const float4* rp = (const float4*)&r_arr[slot * PXS + c * 8];
        float4 r0 = rp[0], r1 = rp[1];
        float pre[4];
        #pragma unroll
        for (int r = 0; r < 4; ++r) {
            float s;
            s  = r0.x * acc[mt][0][r]; s = fmaf(r0.y, acc[mt][1][r], s);
            s  = fmaf(r0.z, acc[mt][2][r], s); s = fmaf(r0.w, acc[mt][3][r], s);
            s  = fmaf(r1.x, acc[mt][4][r], s); s = fmaf(r1.y, acc[mt][5][r], s);
            s  = fmaf(r1.z, acc[mt][6][r], s); s = fmaf(r1.w, acc[mt][7][r], s);
            pre[r] = s + barr[r];
        }
        float s2 = sumquad(pre[0]*pre[0] + pre[1]*pre[1] + pre[2]*pre[2] + pre[3]*pre[3]);
        float scale = s2 * __builtin_amdgcn_rsqf(s2 + EPS) * __builtin_amdgcn_rcpf(1.f + s2);
        float4 o4 = { scale*pre[0], scale*pre[1], scale*pre[2], scale*pre[3] };
        int gh = h + g;
        int px = mt * 16 + l15;
        *(float4*)(out + (((b * 32 + gh) * 32 + px) << 7) + c * 16 + quad * 4) = o4;
    }
}

extern "C" void kernel_launch(void* const* d_in, const int* in_sizes, int n_in,
                              void* d_out, int out_size, void* d_ws, size_t ws_size,
                              hipStream_t stream) {
    const float* x    = (const float*)d_in[0];
    const float* wts  = (const float*)d_in[1];
    const float* bias = (const float*)d_in[2];
    float* out        = (float*)d_out;
    _Float16* w16     = (_Float16*)d_ws;

    prep_weights<<<dim3(640), dim3(256), 0, stream>>>(wts, w16);
    capsule_mfma_kernel<<<dim3(512), dim3(1024), 0, stream>>>(x, w16, bias, out);
}